// Round 4
// baseline (445.766 us; speedup 1.0000x reference)
//
#include <hip/hip_runtime.h>
#include <hip/hip_bf16.h>

typedef unsigned int uint32;
using short8 = __attribute__((ext_vector_type(8))) short;
using ushort4_t = __attribute__((ext_vector_type(4))) unsigned short;
using f32x4  = __attribute__((ext_vector_type(4))) float;

#define B_ 32
#define C_ 256
#define M_ 4096
#define MATF 2097152      // elements per 32-batch matrix set (32*256*256)

#define AS1 __attribute__((address_space(1)))
#define AS3 __attribute__((address_space(3)))

__device__ inline ushort f2bf(float f) {   // compiler conversion path (v_cvt)
  __hip_bfloat16 h = __float2bfloat16(f);
  return __builtin_bit_cast(unsigned short, h);
}
__device__ inline float bf2f(ushort u) {
  uint32 v = ((uint32)u) << 16;
  return __builtin_bit_cast(float, v);
}
__device__ inline void gl_lds16(const ushort* g, ushort* l) {
  __builtin_amdgcn_global_load_lds((const AS1 void*)g, (AS3 void*)l, 16, 0, 0);
}

// ---------------------------------------------------------------------------
// covpool partial: slice s of Gram G[b] = X X^T over k = s*512..+512.
// One block = full 256x256 output from a single shared LDS panel (A==B).
// grid 256 (32 b x 8 s), 1024 threads (16 waves, each a 64x64 quadrant).
// Double-buffered LDS; loads for step s+1 issued before barrier of step s.
// Partials stored bf16.
// ---------------------------------------------------------------------------
__global__ __launch_bounds__(1024)
void covpool_kernel(const float* __restrict__ x, ushort* __restrict__ parts,
                    float* __restrict__ rs) {
  const int bid = blockIdx.x;
  const int b = bid >> 3, s = bid & 7;
  const int kb = s * 512;
  const float* Xb = x + (size_t)b * C_ * M_;
  ushort* P = parts + (size_t)s * MATF + ((size_t)b << 16);

  __shared__ ushort As[2][256 * 64];   // 2 x 32 KB

  const int t    = threadIdx.x;
  const int lane = t & 63;
  const int w    = t >> 6;            // 0..15
  const int wr   = w >> 2, wc = w & 3;
  const int row  = t >> 2;            // 0..255
  const int ch   = t & 3;             // 16-float source chunk

  float rsum = 0.f;
  f32x4 acc[4][4];
#pragma unroll
  for (int m = 0; m < 4; ++m)
#pragma unroll
    for (int n = 0; n < 4; ++n) acc[m][n] = f32x4{0.f, 0.f, 0.f, 0.f};

  const int swzbase = (row & 7) << 4;
  const float* srcbase = Xb + (size_t)row * M_ + ch * 16;

  float4 cv[4];
  {
    const float4* p = (const float4*)(srcbase + kb);
    cv[0] = p[0]; cv[1] = p[1]; cv[2] = p[2]; cv[3] = p[3];
  }

#pragma unroll
  for (int st = 0; st < 8; ++st) {
    float4 nv[4];
    if (st < 7) {
      const float4* p = (const float4*)(srcbase + kb + (st + 1) * 64);
      nv[0] = p[0]; nv[1] = p[1]; nv[2] = p[2]; nv[3] = p[3];
    }
    // convert current chunk and write to LDS buf[st&1]
    char* wbase = (char*)As[st & 1] + row * 128;
#pragma unroll
    for (int q = 0; q < 2; ++q) {
      const float4 a = cv[2 * q], bq = cv[2 * q + 1];
      rsum += a.x + a.y + a.z + a.w + bq.x + bq.y + bq.z + bq.w;
      short8 h;
      h[0] = (short)f2bf(a.x);  h[1] = (short)f2bf(a.y);
      h[2] = (short)f2bf(a.z);  h[3] = (short)f2bf(a.w);
      h[4] = (short)f2bf(bq.x); h[5] = (short)f2bf(bq.y);
      h[6] = (short)f2bf(bq.z); h[7] = (short)f2bf(bq.w);
      *(short8*)(wbase + (((ch * 2 + q) * 16) ^ swzbase)) = h;
    }
    __syncthreads();
    const char* rb_ = (const char*)As[st & 1];
#pragma unroll
    for (int kk = 0; kk < 2; ++kk) {
      short8 af[4], bfr[4];
      const int slot = kk * 4 + (lane >> 4);
#pragma unroll
      for (int m = 0; m < 4; ++m) {
        const int ar = wr * 64 + m * 16 + (lane & 15);
        af[m] = *(const short8*)(rb_ + ar * 128 + ((slot * 16) ^ ((ar & 7) << 4)));
      }
#pragma unroll
      for (int n = 0; n < 4; ++n) {
        const int br = wc * 64 + n * 16 + (lane & 15);
        bfr[n] = *(const short8*)(rb_ + br * 128 + ((slot * 16) ^ ((br & 7) << 4)));
      }
#pragma unroll
      for (int m = 0; m < 4; ++m)
#pragma unroll
        for (int n = 0; n < 4; ++n)
          acc[m][n] = __builtin_amdgcn_mfma_f32_16x16x32_bf16(af[m], bfr[n], acc[m][n], 0, 0, 0);
    }
    if (st < 7) { cv[0] = nv[0]; cv[1] = nv[1]; cv[2] = nv[2]; cv[3] = nv[3]; }
  }

  // per-row sums: 4 staging threads per row are consecutive lanes
  rsum += __shfl_xor(rsum, 1);
  rsum += __shfl_xor(rsum, 2);
  if (ch == 0) rs[b * 2048 + s * 256 + row] = rsum;

#pragma unroll
  for (int m = 0; m < 4; ++m)
#pragma unroll
    for (int n = 0; n < 4; ++n)
#pragma unroll
      for (int r = 0; r < 4; ++r) {
        const int lr = wr * 64 + m * 16 + ((lane >> 4) * 4) + r;
        const int lc = wc * 64 + n * 16 + (lane & 15);
        P[(size_t)lr * C_ + lc] = f2bf(acc[m][n][r]);
      }
}

// ---------------------------------------------------------------------------
// trace from partials: n = sum_i (G_ii/M - mu_i^2); invn, sqrtn
// ---------------------------------------------------------------------------
__global__ __launch_bounds__(256)
void trace_kernel(const ushort* __restrict__ parts, const float* __restrict__ rs,
                  float* __restrict__ invn, float* __restrict__ sqrtn) {
  const int b = blockIdx.x;
  const int i = threadIdx.x;
  const float invM = 1.0f / (float)M_;
  float d = 0.f, m = 0.f;
#pragma unroll
  for (int s = 0; s < 8; ++s) {
    d += bf2f(parts[(size_t)s * MATF + ((size_t)b << 16) + (size_t)i * 257]);
    m += rs[b * 2048 + s * 256 + i];
  }
  const float mu = m * invM;
  float v = d * invM - mu * mu;
#pragma unroll
  for (int o = 32; o > 0; o >>= 1) v += __shfl_xor(v, o);
  __shared__ float wsum[4];
  if ((i & 63) == 0) wsum[i >> 6] = v;
  __syncthreads();
  if (i == 0) {
    const float n = wsum[0] + wsum[1] + wsum[2] + wsum[3];
    invn[b]  = 1.0f / n;
    sqrtn[b] = sqrtf(n);
  }
}

// ---------------------------------------------------------------------------
// reduceprep: cov = (sum_s p_s)/M - mu mu^T (never stored);
// E0 = cov * invn (bf16)  [= trace-normalized Ahat]
// grid 2048 x 256, one 4-element quad per thread
// ---------------------------------------------------------------------------
__global__ __launch_bounds__(256)
void reduceprep_kernel(const ushort* __restrict__ parts, const float* __restrict__ rs,
                       const float* __restrict__ invn, ushort* __restrict__ E0) {
  const int idx = blockIdx.x * 256 + threadIdx.x;   // 524288 quads
  const int b   = idx >> 14;
  const int rem = idx & 16383;
  const int i   = rem >> 6;
  const int j   = (rem & 63) * 4;
  const float invM = 1.0f / (float)M_;
  const ushort4_t* p4 = (const ushort4_t*)parts;

  float g0 = 0.f, g1 = 0.f, g2 = 0.f, g3 = 0.f;
  float mi = 0.f;
  float4 mj = {0.f, 0.f, 0.f, 0.f};
#pragma unroll
  for (int s = 0; s < 8; ++s) {
    const ushort4_t gs = p4[(size_t)s * (MATF / 4) + idx];
    g0 += bf2f(gs[0]); g1 += bf2f(gs[1]); g2 += bf2f(gs[2]); g3 += bf2f(gs[3]);
    const float* rrow = rs + b * 2048 + s * 256;
    mi += rrow[i];
    const float4 ms = *(const float4*)(rrow + j);
    mj.x += ms.x; mj.y += ms.y; mj.z += ms.z; mj.w += ms.w;
  }
  mi *= invM;
  const float in = invn[b];
  ushort4_t ev;
  ev[0] = f2bf((g0 * invM - mi * (mj.x * invM)) * in);
  ev[1] = f2bf((g1 * invM - mi * (mj.y * invM)) * in);
  ev[2] = f2bf((g2 * invM - mi * (mj.z * invM)) * in);
  ev[3] = f2bf((g3 * invM - mi * (mj.w * invM)) * in);
  ((ushort4_t*)E0)[idx] = ev;
}

// ---------------------------------------------------------------------------
// gemm_i0: O = 1.5*A - 0.5 * (A @ B)   (batched 256x256x256, 64x64 tiles,
// 512 blocks XCD-swizzled, 2-phase double-buffered staging via
// global_load_lds with pre-swizzled source).
// If MV: blocks 512..543 instead compute w_out = 1.5*w_in - 0.5*B@w_in
// (w_in==nullptr -> w_in = ones/256). B is the E_k operand.
// ---------------------------------------------------------------------------
template <int MV>
__global__ __launch_bounds__(256)
void gemm_i0(const ushort* __restrict__ A, const ushort* __restrict__ B,
             ushort* __restrict__ O,
             const float* __restrict__ win, float* __restrict__ wout) {
  const int bid0 = blockIdx.x;
  if (MV && bid0 >= 512) {
    // ---- matvec tail: one block per batch ----
    const int b = bid0 - 512;
    const int t = threadIdx.x;
    const ushort* Eb = B + ((size_t)b << 16);
    __shared__ float wsm[256];
    wsm[t] = win ? win[b * 256 + t] : (1.0f / 256.0f);
    __syncthreads();
    float acc = 0.f;
#pragma unroll 4
    for (int k = 0; k < 256; ++k) acc += bf2f(Eb[(size_t)k * 256 + t]) * wsm[k];
    wout[b * 256 + t] = 1.5f * wsm[t] - 0.5f * acc;
    return;
  }

  const int bid = (bid0 & 7) * 64 + (bid0 >> 3);   // XCD swizzle (512%8==0)
  const int b    = bid >> 4;
  const int tile = bid & 15;
  const int rb   = (tile >> 2) * 64;
  const int cb   = (tile & 3) * 64;
  const ushort* Ap = A + ((size_t)b << 16) + rb * C_;
  const ushort* Bp = B + ((size_t)b << 16) + cb * C_;
  ushort* Op = O + ((size_t)b << 16);

  __shared__ ushort As[2][64 * 64];
  __shared__ ushort Bs[2][64 * 64];

  const int t    = threadIdx.x;
  const int lane = t & 63;
  const int wid  = t >> 6;
  const int wr   = wid >> 1, wc = wid & 1;   // wave -> 32x32 subtile

  // staging source geometry (per issue q: rows q*32 + (t>>3))
  const int srow0 = t >> 3;
  const int sc0   = (t & 7) ^ (srow0 & 7);   // pre-swizzled 16B chunk
  const int srow1 = 32 + srow0;
  const int sc1   = (t & 7) ^ (srow1 & 7);

  f32x4 acc[2][2];
#pragma unroll
  for (int m = 0; m < 2; ++m)
#pragma unroll
    for (int n = 0; n < 2; ++n) acc[m][n] = f32x4{0.f, 0.f, 0.f, 0.f};

#define STAGE(k0, c)                                                            \
  do {                                                                          \
    gl_lds16(Ap + (size_t)srow0 * C_ + (k0) + sc0 * 8, &As[c][0]    + wid*512); \
    gl_lds16(Ap + (size_t)srow1 * C_ + (k0) + sc1 * 8, &As[c][2048] + wid*512); \
    gl_lds16(Bp + (size_t)srow0 * C_ + (k0) + sc0 * 8, &Bs[c][0]    + wid*512); \
    gl_lds16(Bp + (size_t)srow1 * C_ + (k0) + sc1 * 8, &Bs[c][2048] + wid*512); \
  } while (0)

#define COMPUTE(c)                                                              \
  do {                                                                          \
    const char* ab = (const char*)As[c];                                        \
    const char* bb = (const char*)Bs[c];                                        \
    _Pragma("unroll")                                                           \
    for (int kk = 0; kk < 2; ++kk) {                                            \
      short8 af[2], bfr[2];                                                     \
      const int slot = kk * 4 + (lane >> 4);                                    \
      _Pragma("unroll")                                                         \
      for (int m = 0; m < 2; ++m) {                                             \
        const int ar = wr * 32 + m * 16 + (lane & 15);                          \
        af[m] = *(const short8*)(ab + ar * 128 + ((slot * 16) ^ ((ar & 7) << 4))); \
      }                                                                         \
      _Pragma("unroll")                                                         \
      for (int n = 0; n < 2; ++n) {                                             \
        const int br = wc * 32 + n * 16 + (lane & 15);                          \
        bfr[n] = *(const short8*)(bb + br * 128 + ((slot * 16) ^ ((br & 7) << 4))); \
      }                                                                         \
      _Pragma("unroll")                                                         \
      for (int m = 0; m < 2; ++m)                                               \
        _Pragma("unroll")                                                       \
        for (int n = 0; n < 2; ++n)                                             \
          acc[m][n] = __builtin_amdgcn_mfma_f32_16x16x32_bf16(af[m], bfr[n], acc[m][n], 0, 0, 0); \
    }                                                                           \
  } while (0)

  STAGE(0, 0);
  __syncthreads();
  int cur = 0;
#pragma unroll
  for (int k0 = 64; k0 < 256; k0 += 64) {
    STAGE(k0, cur ^ 1);
    COMPUTE(cur);
    __syncthreads();
    cur ^= 1;
  }
  COMPUTE(cur);
#undef STAGE
#undef COMPUTE

#pragma unroll
  for (int m = 0; m < 2; ++m)
#pragma unroll
    for (int n = 0; n < 2; ++n)
#pragma unroll
      for (int r = 0; r < 4; ++r) {
        const int lr = wr * 32 + m * 16 + ((lane >> 4) * 4) + r;
        const int lc = wc * 32 + n * 16 + (lane & 15);
        const float o = 1.5f * bf2f(Ap[lr * C_ + (cb + lc)]) - 0.5f * acc[m][n][r];
        Op[(size_t)(rb + lr) * C_ + (cb + lc)] = f2bf(o);
      }
}

// ---------------------------------------------------------------------------
// final: w5 = 1.5 w4 - 0.5 E4 w4 ; v = sqrtn * (E0 w5) ; MLP -> a[b][c]
// ---------------------------------------------------------------------------
__global__ __launch_bounds__(256)
void final_kernel(const ushort* __restrict__ E4, const ushort* __restrict__ E0,
                  const float* __restrict__ wvin, const float* __restrict__ sqrtn,
                  const float* __restrict__ w1, const float* __restrict__ b1,
                  const float* __restrict__ w2, const float* __restrict__ b2,
                  float* __restrict__ a) {
  const int b = blockIdx.x;
  const int c = threadIdx.x;
  __shared__ float w4s[C_], w5[C_], vv[C_], h[32];
  const ushort* E4b = E4 + ((size_t)b << 16);
  const ushort* E0b = E0 + ((size_t)b << 16);

  w4s[c] = wvin[b * C_ + c];
  __syncthreads();
  float acc = 0.f;
#pragma unroll 4
  for (int k = 0; k < C_; ++k) acc += bf2f(E4b[(size_t)k * C_ + c]) * w4s[k];
  w5[c] = 1.5f * w4s[c] - 0.5f * acc;
  __syncthreads();

  float acc2 = 0.f;
#pragma unroll 4
  for (int k = 0; k < C_; ++k) acc2 += bf2f(E0b[(size_t)k * C_ + c]) * w5[k];
  vv[c] = acc2 * sqrtn[b];
  __syncthreads();

  if (c < 32) {
    float hh = b1[c];
    for (int k = 0; k < C_; ++k) hh += w1[c * C_ + k] * vv[k];
    h[c] = fmaxf(hh, 0.0f);
  }
  __syncthreads();

  float aa = b2[c];
#pragma unroll
  for (int o = 0; o < 32; ++o) aa += w2[c * 32 + o] * h[o];
  a[b * C_ + c] = 1.0f / (1.0f + expf(-aa));
}

// ---------------------------------------------------------------------------
// scale: out = a[b][c] * x
// ---------------------------------------------------------------------------
__global__ __launch_bounds__(256)
void scale_kernel(const float* __restrict__ x, const float* __restrict__ a,
                  float* __restrict__ out) {
  const int stride = gridDim.x * blockDim.x;
  const int n4 = B_ * C_ * M_ / 4;   // 8388608
  for (int i = blockIdx.x * blockDim.x + threadIdx.x; i < n4; i += stride) {
    const float4 v = ((const float4*)x)[i];
    const float s = a[i >> 10];
    float4 o = { v.x * s, v.y * s, v.z * s, v.w * s };
    ((float4*)out)[i] = o;
  }
}

// ---------------------------------------------------------------------------
extern "C" void kernel_launch(void* const* d_in, const int* in_sizes, int n_in,
                              void* d_out, int out_size, void* d_ws, size_t ws_size,
                              hipStream_t stream) {
  const float* x  = (const float*)d_in[0];
  const float* w1 = (const float*)d_in[1];
  const float* b1 = (const float*)d_in[2];
  const float* w2 = (const float*)d_in[3];
  const float* b2 = (const float*)d_in[4];
  float* out = (float*)d_out;

  float* ws = (float*)d_ws;
  ushort* partsbf = (ushort*)ws;                  // 8*MATF ushorts (32 MB)
  float* rs    = ws + 4 * (size_t)MATF;           // 32*2048 fp32
  float* invn  = rs + 65536;
  float* sqrtn = invn + 32;
  float* a     = sqrtn + 32;                      // 32*256
  float* wvA   = a + 8192;                        // 32*256
  float* wvB   = wvA + 8192;
  ushort* E0 = (ushort*)(wvB + 8192);             // each MATF ushorts (4 MB)
  ushort* EB = E0 + (size_t)MATF;
  ushort* EC = EB + (size_t)MATF;
  ushort* U  = EC + (size_t)MATF;

  covpool_kernel<<<256, 1024, 0, stream>>>(x, partsbf, rs);
  trace_kernel<<<32, 256, 0, stream>>>(partsbf, rs, invn, sqrtn);
  reduceprep_kernel<<<2048, 256, 0, stream>>>(partsbf, rs, invn, E0);

  // E-form NS: per k: U = 1.5E-0.5E@E (+ w <- 1.5w-0.5Ew), E' = 1.5U-0.5U@E
  gemm_i0<1><<<544, 256, 0, stream>>>(E0, E0, U, nullptr, wvA);   // k=0, w0 synth
  gemm_i0<0><<<512, 256, 0, stream>>>(U, E0, EB, nullptr, nullptr); // E1
  gemm_i0<1><<<544, 256, 0, stream>>>(EB, EB, U, wvA, wvB);       // k=1
  gemm_i0<0><<<512, 256, 0, stream>>>(U, EB, EC, nullptr, nullptr); // E2
  gemm_i0<1><<<544, 256, 0, stream>>>(EC, EC, U, wvB, wvA);       // k=2
  gemm_i0<0><<<512, 256, 0, stream>>>(U, EC, EB, nullptr, nullptr); // E3
  gemm_i0<1><<<544, 256, 0, stream>>>(EB, EB, U, wvA, wvB);       // k=3
  gemm_i0<0><<<512, 256, 0, stream>>>(U, EB, EC, nullptr, nullptr); // E4

  final_kernel<<<32, 256, 0, stream>>>(EC, E0, wvB, sqrtn, w1, b1, w2, b2, a);
  scale_kernel<<<4096, 256, 0, stream>>>(x, a, out);
}